// Round 11
// baseline (443.606 us; speedup 1.0000x reference)
//
#include <hip/hip_runtime.h>
#include <stdint.h>
#include <stddef.h>

// Causal GQA prefill attention, MI355X gfx950.
// Round 13: round-12's intra-step changes with the grid REVERTED to the
// known-good order. r12's (c) grid reorder was catastrophic (155->345us,
// FETCH 172->847MB): co-resident blocks spanned all 16 K/V streams (~268MB
// working set, no concurrent sharing) instead of sharing one 16.8MB stream.
// RULE (3rd confirmation, r5/r12): the dispatch-order/global-stream locality
// of this kernel is load-bearing -- grid = (pairp fast, h, b) stays frozen.
// This round cleanly A/Bs the two unconfounded r12 changes:
//  (a) subtile-0 K-frag ds_reads issue FIRST each step (jump the DS queue
//      ahead of ~100 staging-write wave-insts that delay the first QK MFMA).
//  (b) QK accumulator split into two 2-deep MFMA chains + vector add (was one
//      4-deep serial chain, ~50-60 cyc exposed latency per subtile).
// Kept: 512 thr / 8 waves / 16 q-rows per wave (16 waves/CU, register-locked
// geometry); padded 1040B LDS strides; software-pipelined staging, one
// barrier/step (r10); b128 PV V-image (r10); per-subtile fusion + kt_lim skip
// + setprio (r11); flat fixed-base softmax (C=0) + MFMA ones-column
// denominator (r9); balanced {p,15-p} q-block pairing (34 steps).
// Verified math: S^T = K*Q^T via mfma_16x16x32_bf16; C-layout = A-layout of
// mfma_16x16x16bf16_1k, so P feeds PV from registers.
//
// LDS tile image (66,560 B both buffers; elems):
//   K-part: chunk c 0..15 at c*520 + key*8 : K[key][c*8..c*8+7]
//   V-part: base 8320; unit u at u*520, m 0..3 at m*128, l15 at l15*8:
//           8 elems = rows 4u..4u+3 of d=32m+l15, then of d=32m+16+l15

#define S_LEN   2048
#define HQ      32
#define HKV     8
#define DH      128
#define QSTRIDE (HQ*DH)
#define KSTRIDE (HKV*DH)
// (1/sqrt(128)) * log2(e): softmax in exp2 space
#define SCALE_L2 0.12751139830213113f

#define KTILE      64
#define NTILES     (S_LEN/KTILE)          // 32
#define CSTRIDE    520                    // padded chunk/unit stride (elems)
#define KPART      (16*CSTRIDE)           // 8320 elems
#define TILE_ELEMS (KPART + 16*CSTRIDE)   // 16640 elems (33,280 B)
#define TSTEPS     34                     // nst0 + nst1, constant by pairing

typedef __bf16 bf16;
typedef short        s16x4 __attribute__((ext_vector_type(4)));
typedef short        s16x8 __attribute__((ext_vector_type(8)));
typedef float        f32x4 __attribute__((ext_vector_type(4)));
typedef unsigned int u32x2 __attribute__((ext_vector_type(2)));
typedef unsigned int u32x4 __attribute__((ext_vector_type(4)));

__device__ __forceinline__ unsigned int pk2(float a, float b) {
  union { bf16 h[2]; unsigned int u; } x;
  x.h[0] = (bf16)a; x.h[1] = (bf16)b;    // fptrunc = RNE
  return x.u;
}

__device__ __forceinline__ int koff(int chunk, int key) {
  return chunk*CSTRIDE + key*8;
}

__global__ __launch_bounds__(512, 4)
void attn_fwd(const float* __restrict__ qg, const float* __restrict__ kg,
              const float* __restrict__ vg, float* __restrict__ og) {
  __shared__ bf16 smem[2*TILE_ELEMS];    // 66,560 B, double-buffered

  const int tid   = threadIdx.x;
  const int lane  = tid & 63;
  const int wave  = tid >> 6;            // 8 waves/block
  const int l15   = lane & 15;
  const int quad  = lane >> 4;
  const int pairp = blockIdx.x;          // 0..7  (fast dim -- FROZEN, r12)
  const int h     = blockIdx.y;          // 0..31
  const int b     = blockIdx.z;          // 0..1
  const int hkv   = h >> 2;

  // staging roles: 512 threads cover the 64x128 K tile and 64x128 V tile
  const int fk_key = tid >> 3, fk_cg = tid & 7;      // K: 2 chunks / thread
  const int fv_u   = tid & 15, fv_dq = tid >> 4;     // V: unit, d-quad
  float4 fkx[4], fvx[4];

  auto load_regs = [&](int t) {
    const float* kp = kg + (size_t)(b*S_LEN + t*KTILE + fk_key)*KSTRIDE
                         + hkv*DH + fk_cg*16;
#pragma unroll
    for (int i = 0; i < 4; ++i) fkx[i] = ((const float4*)kp)[i];
    const int d0 = fv_dq*4;
#pragma unroll
    for (int j = 0; j < 4; ++j)
      fvx[j] = *(const float4*)(vg + (size_t)(b*S_LEN + t*KTILE + fv_u*4 + j)*KSTRIDE
                                   + hkv*DH + d0);
  };
  auto store_tile = [&](int bi) {
    bf16* kb = smem + bi*TILE_ELEMS;
#pragma unroll
    for (int ii = 0; ii < 2; ++ii) {
      u32x4 w;
      w[0] = pk2(fkx[2*ii].x,   fkx[2*ii].y);   w[1] = pk2(fkx[2*ii].z,   fkx[2*ii].w);
      w[2] = pk2(fkx[2*ii+1].x, fkx[2*ii+1].y); w[3] = pk2(fkx[2*ii+1].z, fkx[2*ii+1].w);
      *(u32x4*)(kb + koff(fk_cg*2 + ii, fk_key)) = w;
    }
    bf16* vb = kb + KPART;
    const float* g0 = (const float*)&fvx[0];
    const float* g1 = (const float*)&fvx[1];
    const float* g2 = (const float*)&fvx[2];
    const float* g3 = (const float*)&fvx[3];
#pragma unroll
    for (int i = 0; i < 4; ++i) {
      const int d = fv_dq*4 + i;
      u32x2 w;
      w[0] = pk2(g0[i], g1[i]);      // rows 4u+0, 4u+1
      w[1] = pk2(g2[i], g3[i]);      // rows 4u+2, 4u+3
      *(u32x2*)(vb + fv_u*CSTRIDE + (d >> 5)*128 + (d & 15)*8
                   + ((d >> 4) & 1)*4) = w;
    }
  };

  f32x4 oacc[9];                         // [0..7]=O d-cols, [8]=denominator l
  u32x4 qf[4];
  const s16x4 ones = { (short)0x3F80, (short)0x3F80,
                       (short)0x3F80, (short)0x3F80 };  // bf16 1.0 x4

  const int qbs[2] = { pairp, 15 - pairp };     // balanced: 34 steps total
  const int nst0   = qbs[0]*2 + 2;

  // pipeline prologue: tile0 -> buf0, tile1 in regs/in flight
  load_regs(0);
  store_tile(0);
  load_regs(1);                                 // nst0 >= 2, tile 1 exists
  __syncthreads();                              // buf0 visible

  int gs = 0;                                   // flat step counter
#pragma unroll 1
  for (int item = 0; item < 2; ++item) {
    const int qblk = qbs[item];
    const int qw   = qblk*128 + wave*16;        // this wave's 16 q-rows
    const int nst  = qblk*2 + 2;

    // Q fragments (B-operand of S^T = K*Q^T), scale*log2e folded in
    {
      const float* qp = qg + (size_t)(b*S_LEN + qw + l15)*QSTRIDE
                           + h*DH + quad*8;
#pragma unroll
      for (int c = 0; c < 4; ++c) {
        const float4 a4 = ((const float4*)(qp + c*32))[0];
        const float4 b4 = ((const float4*)(qp + c*32))[1];
        u32x4 w;
        w[0] = pk2(a4.x*SCALE_L2, a4.y*SCALE_L2);
        w[1] = pk2(a4.z*SCALE_L2, a4.w*SCALE_L2);
        w[2] = pk2(b4.x*SCALE_L2, b4.y*SCALE_L2);
        w[3] = pk2(b4.z*SCALE_L2, b4.w*SCALE_L2);
        qf[c] = w;
      }
    }
#pragma unroll
    for (int nd = 0; nd < 9; ++nd) oacc[nd] = (f32x4){0.f, 0.f, 0.f, 0.f};

#pragma unroll 1
    for (int i = 0; i < nst; ++i, ++gs) {
      const int k0  = i*KTILE;
      const int buf = gs & 1;
      const bf16* kb = smem + buf*TILE_ELEMS;
      const bf16* vb = kb + KPART;
      const bool active = (k0 <= qw + 15);     // wave-uniform causal
      const int  qgl    = qw + l15;
      const int  kt_lim = active ? (((qw + 15 - k0) >> 4) + 1 < 4
                                    ? ((qw + 15 - k0) >> 4) + 1 : 4) : 0;

      // per-subtile body: QK (2 chains) -> mask/exp/pack -> PV
      auto do_subtile = [&](int kt, u32x4 f0, u32x4 f1, u32x4 f2, u32x4 f3) {
        f32x4 acc_a = (f32x4){0.f, 0.f, 0.f, 0.f};
        f32x4 acc_b = (f32x4){0.f, 0.f, 0.f, 0.f};
        __builtin_amdgcn_s_setprio(1);
        acc_a = __builtin_amdgcn_mfma_f32_16x16x32_bf16(
            __builtin_bit_cast(s16x8, f0), __builtin_bit_cast(s16x8, qf[0]),
            acc_a, 0, 0, 0);
        acc_b = __builtin_amdgcn_mfma_f32_16x16x32_bf16(
            __builtin_bit_cast(s16x8, f2), __builtin_bit_cast(s16x8, qf[2]),
            acc_b, 0, 0, 0);
        acc_a = __builtin_amdgcn_mfma_f32_16x16x32_bf16(
            __builtin_bit_cast(s16x8, f1), __builtin_bit_cast(s16x8, qf[1]),
            acc_a, 0, 0, 0);
        acc_b = __builtin_amdgcn_mfma_f32_16x16x32_bf16(
            __builtin_bit_cast(s16x8, f3), __builtin_bit_cast(s16x8, qf[3]),
            acc_b, 0, 0, 0);
        __builtin_amdgcn_s_setprio(0);
        f32x4 sacc = acc_a + acc_b;

        if (k0 + kt*16 + 15 > qw) {            // wave-uniform diagonal subtile
#pragma unroll
          for (int r = 0; r < 4; ++r) {
            const int key = k0 + kt*16 + quad*4 + r;
            if (key > qgl) sacc[r] = -3e38f;
          }
        }
        s16x4 pa;
        {
          union { unsigned int uu[2]; s16x4 s; } u;
          u.uu[0] = pk2(__builtin_amdgcn_exp2f(sacc[0]),
                        __builtin_amdgcn_exp2f(sacc[1]));
          u.uu[1] = pk2(__builtin_amdgcn_exp2f(sacc[2]),
                        __builtin_amdgcn_exp2f(sacc[3]));
          pa = u.s;
        }
        const bf16* vu = vb + (kt*4 + quad)*CSTRIDE + l15*8;
        __builtin_amdgcn_s_setprio(1);
#pragma unroll
        for (int m = 0; m < 4; ++m) {
          const s16x8 v8 = *(const s16x8*)(vu + m*128);
          const s16x4 blo = __builtin_shufflevector(v8, v8, 0, 1, 2, 3);
          const s16x4 bhi = __builtin_shufflevector(v8, v8, 4, 5, 6, 7);
          oacc[2*m]   = __builtin_amdgcn_mfma_f32_16x16x16bf16_1k(
              pa, blo, oacc[2*m],   0, 0, 0);
          oacc[2*m+1] = __builtin_amdgcn_mfma_f32_16x16x16bf16_1k(
              pa, bhi, oacc[2*m+1], 0, 0, 0);
        }
        oacc[8] = __builtin_amdgcn_mfma_f32_16x16x16bf16_1k(
            pa, ones, oacc[8], 0, 0, 0);
        __builtin_amdgcn_s_setprio(0);
      };

      // (a) subtile-0 K-frag reads FIRST: they jump the DS queue ahead of the
      // staging writes, so subtile-0's MFMA starts ~100 cyc earlier.
      u32x4 a00, a01, a02, a03;
      if (active) {
        a00 = *(const u32x4*)(kb + koff(0*4 + quad, l15));
        a01 = *(const u32x4*)(kb + koff(1*4 + quad, l15));
        a02 = *(const u32x4*)(kb + koff(2*4 + quad, l15));
        a03 = *(const u32x4*)(kb + koff(3*4 + quad, l15));
      }

      // pipeline: stage tile gs+1 into buf^1, issue loads for gs+2
      const int g1 = gs + 1, g2 = gs + 2;
      if (g1 < TSTEPS) store_tile(buf ^ 1);     // regs hold tile g1
      if (g2 < TSTEPS) load_regs(g2 < nst0 ? g2 : g2 - nst0);

      if (active) {
        do_subtile(0, a00, a01, a02, a03);
#pragma unroll
        for (int kt = 1; kt < 4; ++kt) {
          if (kt < kt_lim) {                   // wave-uniform
            const u32x4 f0 = *(const u32x4*)(kb + koff(0*4 + quad, kt*16 + l15));
            const u32x4 f1 = *(const u32x4*)(kb + koff(1*4 + quad, kt*16 + l15));
            const u32x4 f2 = *(const u32x4*)(kb + koff(2*4 + quad, kt*16 + l15));
            const u32x4 f3 = *(const u32x4*)(kb + koff(3*4 + quad, kt*16 + l15));
            do_subtile(kt, f0, f1, f2, f3);
          }
        }
      }
      __syncthreads();                         // buf^1 staged; buf reads done
    }

    // ---- epilogue: O / l, fp32 store (l already per-lane in row layout) ---
#pragma unroll
    for (int r = 0; r < 4; ++r) {
      const float inv = 1.0f / oacc[8][r];
      const size_t base = (size_t)(b*S_LEN + qw + quad*4 + r)*QSTRIDE
                        + h*DH + l15;
#pragma unroll
      for (int nd = 0; nd < 8; ++nd)
        og[base + nd*16] = oacc[nd][r] * inv;
    }
  }
}

extern "C" void kernel_launch(void* const* d_in, const int* in_sizes, int n_in,
                              void* d_out, int out_size, void* d_ws, size_t ws_size,
                              hipStream_t stream) {
  const float* q = (const float*)d_in[0];
  const float* k = (const float*)d_in[1];
  const float* v = (const float*)d_in[2];
  float* out = (float*)d_out;
  (void)d_ws; (void)ws_size;
  dim3 grid(8, HQ, 2);       // FROZEN: pairp fast, h, b (r5/r12 lesson)
  dim3 block(512);
  attn_fwd<<<grid, block, 0, stream>>>(q, k, v, out);
}

// Round 12
// 246.632 us; speedup vs baseline: 1.7987x; 1.7987x over previous
//
#include <hip/hip_runtime.h>
#include <stdint.h>
#include <stddef.h>

// Causal GQA prefill attention, MI355X gfx950.
// Round 14: r11 structure (155.3us best) + ONE spill-safe delta (QK chain
// split). r13 post-mortem: r12/r13's 350us regressions were REGISTER SPILL --
// holding 4 K-frags (16 VGPRs) live across store_tile/load_regs pushed the
// allocator over the cliff; 530MB extra WRITE_SIZE = 64B x 512thr x 512blk x
// 34 steps of scratch traffic. RULE: no live ranges may cross the staging
// code; the allocator sits a few regs from the cliff.
// GRID RULE (r5/r12): grid = (pairp fast, h, b) frozen; dispatch-order
// locality keeps the 8 same-(h,b) blocks sharing one 16.8MB K/V stream in L2.
//
// Delta vs r11: QK accumulator split into two 2-deep MFMA chains + vector add
// (was one 4-deep serial chain); reads stay in their original post-staging
// position inside the subtile body (+4 transient regs, innermost scope only).
//
// Kept from r11: 512 thr / 8 waves / 16 q-rows per wave (16 waves/CU,
// register-locked geometry); padded 1040B LDS strides (<=2-way banks);
// software-pipelined staging, one barrier/step (r10); b128 PV V-image (r10);
// per-subtile fusion + kt_lim masked-subtile skip + setprio (r11); flat
// fixed-base softmax (C=0) + MFMA ones-column denominator (r9); balanced
// {p,15-p} q-block pairing (34 steps).
// Verified math: S^T = K*Q^T via mfma_16x16x32_bf16; C-layout = A-layout of
// mfma_16x16x16bf16_1k, so P feeds PV from registers.
//
// LDS tile image (66,560 B both buffers; elems):
//   K-part: chunk c 0..15 at c*520 + key*8 : K[key][c*8..c*8+7]
//   V-part: base 8320; unit u at u*520, m 0..3 at m*128, l15 at l15*8:
//           8 elems = rows 4u..4u+3 of d=32m+l15, then of d=32m+16+l15

#define S_LEN   2048
#define HQ      32
#define HKV     8
#define DH      128
#define QSTRIDE (HQ*DH)
#define KSTRIDE (HKV*DH)
// (1/sqrt(128)) * log2(e): softmax in exp2 space
#define SCALE_L2 0.12751139830213113f

#define KTILE      64
#define NTILES     (S_LEN/KTILE)          // 32
#define CSTRIDE    520                    // padded chunk/unit stride (elems)
#define KPART      (16*CSTRIDE)           // 8320 elems
#define TILE_ELEMS (KPART + 16*CSTRIDE)   // 16640 elems (33,280 B)
#define TSTEPS     34                     // nst0 + nst1, constant by pairing

typedef __bf16 bf16;
typedef short        s16x4 __attribute__((ext_vector_type(4)));
typedef short        s16x8 __attribute__((ext_vector_type(8)));
typedef float        f32x4 __attribute__((ext_vector_type(4)));
typedef unsigned int u32x2 __attribute__((ext_vector_type(2)));
typedef unsigned int u32x4 __attribute__((ext_vector_type(4)));

__device__ __forceinline__ unsigned int pk2(float a, float b) {
  union { bf16 h[2]; unsigned int u; } x;
  x.h[0] = (bf16)a; x.h[1] = (bf16)b;    // fptrunc = RNE
  return x.u;
}

__device__ __forceinline__ int koff(int chunk, int key) {
  return chunk*CSTRIDE + key*8;
}

__global__ __launch_bounds__(512, 4)
void attn_fwd(const float* __restrict__ qg, const float* __restrict__ kg,
              const float* __restrict__ vg, float* __restrict__ og) {
  __shared__ bf16 smem[2*TILE_ELEMS];    // 66,560 B, double-buffered

  const int tid   = threadIdx.x;
  const int lane  = tid & 63;
  const int wave  = tid >> 6;            // 8 waves/block
  const int l15   = lane & 15;
  const int quad  = lane >> 4;
  const int pairp = blockIdx.x;          // 0..7  (fast dim -- FROZEN)
  const int h     = blockIdx.y;          // 0..31
  const int b     = blockIdx.z;          // 0..1
  const int hkv   = h >> 2;

  // staging roles: 512 threads cover the 64x128 K tile and 64x128 V tile
  const int fk_key = tid >> 3, fk_cg = tid & 7;      // K: 2 chunks / thread
  const int fv_u   = tid & 15, fv_dq = tid >> 4;     // V: unit, d-quad
  float4 fkx[4], fvx[4];

  auto load_regs = [&](int t) {
    const float* kp = kg + (size_t)(b*S_LEN + t*KTILE + fk_key)*KSTRIDE
                         + hkv*DH + fk_cg*16;
#pragma unroll
    for (int i = 0; i < 4; ++i) fkx[i] = ((const float4*)kp)[i];
    const int d0 = fv_dq*4;
#pragma unroll
    for (int j = 0; j < 4; ++j)
      fvx[j] = *(const float4*)(vg + (size_t)(b*S_LEN + t*KTILE + fv_u*4 + j)*KSTRIDE
                                   + hkv*DH + d0);
  };
  auto store_tile = [&](int bi) {
    bf16* kb = smem + bi*TILE_ELEMS;
#pragma unroll
    for (int ii = 0; ii < 2; ++ii) {
      u32x4 w;
      w[0] = pk2(fkx[2*ii].x,   fkx[2*ii].y);   w[1] = pk2(fkx[2*ii].z,   fkx[2*ii].w);
      w[2] = pk2(fkx[2*ii+1].x, fkx[2*ii+1].y); w[3] = pk2(fkx[2*ii+1].z, fkx[2*ii+1].w);
      *(u32x4*)(kb + koff(fk_cg*2 + ii, fk_key)) = w;
    }
    bf16* vb = kb + KPART;
    const float* g0 = (const float*)&fvx[0];
    const float* g1 = (const float*)&fvx[1];
    const float* g2 = (const float*)&fvx[2];
    const float* g3 = (const float*)&fvx[3];
#pragma unroll
    for (int i = 0; i < 4; ++i) {
      const int d = fv_dq*4 + i;
      u32x2 w;
      w[0] = pk2(g0[i], g1[i]);      // rows 4u+0, 4u+1
      w[1] = pk2(g2[i], g3[i]);      // rows 4u+2, 4u+3
      *(u32x2*)(vb + fv_u*CSTRIDE + (d >> 5)*128 + (d & 15)*8
                   + ((d >> 4) & 1)*4) = w;
    }
  };

  f32x4 oacc[9];                         // [0..7]=O d-cols, [8]=denominator l
  u32x4 qf[4];
  const s16x4 ones = { (short)0x3F80, (short)0x3F80,
                       (short)0x3F80, (short)0x3F80 };  // bf16 1.0 x4

  const int qbs[2] = { pairp, 15 - pairp };     // balanced: 34 steps total
  const int nst0   = qbs[0]*2 + 2;

  // pipeline prologue: tile0 -> buf0, tile1 in regs/in flight
  load_regs(0);
  store_tile(0);
  load_regs(1);                                 // nst0 >= 2, tile 1 exists
  __syncthreads();                              // buf0 visible

  int gs = 0;                                   // flat step counter
#pragma unroll 1
  for (int item = 0; item < 2; ++item) {
    const int qblk = qbs[item];
    const int qw   = qblk*128 + wave*16;        // this wave's 16 q-rows
    const int nst  = qblk*2 + 2;

    // Q fragments (B-operand of S^T = K*Q^T), scale*log2e folded in
    {
      const float* qp = qg + (size_t)(b*S_LEN + qw + l15)*QSTRIDE
                           + h*DH + quad*8;
#pragma unroll
      for (int c = 0; c < 4; ++c) {
        const float4 a4 = ((const float4*)(qp + c*32))[0];
        const float4 b4 = ((const float4*)(qp + c*32))[1];
        u32x4 w;
        w[0] = pk2(a4.x*SCALE_L2, a4.y*SCALE_L2);
        w[1] = pk2(a4.z*SCALE_L2, a4.w*SCALE_L2);
        w[2] = pk2(b4.x*SCALE_L2, b4.y*SCALE_L2);
        w[3] = pk2(b4.z*SCALE_L2, b4.w*SCALE_L2);
        qf[c] = w;
      }
    }
#pragma unroll
    for (int nd = 0; nd < 9; ++nd) oacc[nd] = (f32x4){0.f, 0.f, 0.f, 0.f};

#pragma unroll 1
    for (int i = 0; i < nst; ++i, ++gs) {
      const int k0  = i*KTILE;
      const int buf = gs & 1;
      // ---- pipeline: stage tile gs+1 into buf^1, issue loads for gs+2 ----
      // (no value may stay live across this region -- r13 spill lesson)
      const int g1 = gs + 1, g2 = gs + 2;
      if (g1 < TSTEPS) store_tile(buf ^ 1);     // regs hold tile g1
      if (g2 < TSTEPS) load_regs(g2 < nst0 ? g2 : g2 - nst0);

      if (k0 <= qw + 15) {                     // wave-uniform causal skip
        const bf16* kb = smem + buf*TILE_ELEMS;
        const bf16* vb = kb + KPART;
        const int qgl = qw + l15;
        // subtiles kt with k0+16*kt > qw+15 are fully masked: skip them
        const int kt_lim = min(4, ((qw + 15 - k0) >> 4) + 1);

#pragma unroll
        for (int kt = 0; kt < 4; ++kt) {
          if (kt < kt_lim) {                   // wave-uniform
            // ---- S^T(kt) = K_sub * Q^T : two 2-deep chains (r14 delta) ----
            f32x4 acc_a = (f32x4){0.f, 0.f, 0.f, 0.f};
            f32x4 acc_b = (f32x4){0.f, 0.f, 0.f, 0.f};
            __builtin_amdgcn_s_setprio(1);
            {
              const u32x4 af0 = *(const u32x4*)(kb + koff(0*4 + quad, kt*16 + l15));
              acc_a = __builtin_amdgcn_mfma_f32_16x16x32_bf16(
                  __builtin_bit_cast(s16x8, af0), __builtin_bit_cast(s16x8, qf[0]),
                  acc_a, 0, 0, 0);
              const u32x4 af1 = *(const u32x4*)(kb + koff(1*4 + quad, kt*16 + l15));
              acc_b = __builtin_amdgcn_mfma_f32_16x16x32_bf16(
                  __builtin_bit_cast(s16x8, af1), __builtin_bit_cast(s16x8, qf[1]),
                  acc_b, 0, 0, 0);
              const u32x4 af2 = *(const u32x4*)(kb + koff(2*4 + quad, kt*16 + l15));
              acc_a = __builtin_amdgcn_mfma_f32_16x16x32_bf16(
                  __builtin_bit_cast(s16x8, af2), __builtin_bit_cast(s16x8, qf[2]),
                  acc_a, 0, 0, 0);
              const u32x4 af3 = *(const u32x4*)(kb + koff(3*4 + quad, kt*16 + l15));
              acc_b = __builtin_amdgcn_mfma_f32_16x16x32_bf16(
                  __builtin_bit_cast(s16x8, af3), __builtin_bit_cast(s16x8, qf[3]),
                  acc_b, 0, 0, 0);
            }
            __builtin_amdgcn_s_setprio(0);
            f32x4 sacc = acc_a + acc_b;

            // ---- mask + P = exp2(s'), fixed base C=0 ----
            if (k0 + kt*16 + 15 > qw) {        // wave-uniform diagonal subtile
#pragma unroll
              for (int r = 0; r < 4; ++r) {
                const int key = k0 + kt*16 + quad*4 + r;
                if (key > qgl) sacc[r] = -3e38f;
              }
            }
            s16x4 pa;
            {
              union { unsigned int uu[2]; s16x4 s; } u;
              u.uu[0] = pk2(__builtin_amdgcn_exp2f(sacc[0]),
                            __builtin_amdgcn_exp2f(sacc[1]));
              u.uu[1] = pk2(__builtin_amdgcn_exp2f(sacc[2]),
                            __builtin_amdgcn_exp2f(sacc[3]));
              pa = u.s;
            }

            // ---- O += P(kt) * V(kt); l rides nd=8 ----
            const bf16* vu = vb + (kt*4 + quad)*CSTRIDE + l15*8;
            __builtin_amdgcn_s_setprio(1);
#pragma unroll
            for (int m = 0; m < 4; ++m) {
              const s16x8 v8 = *(const s16x8*)(vu + m*128);
              const s16x4 blo = __builtin_shufflevector(v8, v8, 0, 1, 2, 3);
              const s16x4 bhi = __builtin_shufflevector(v8, v8, 4, 5, 6, 7);
              oacc[2*m]   = __builtin_amdgcn_mfma_f32_16x16x16bf16_1k(
                  pa, blo, oacc[2*m],   0, 0, 0);
              oacc[2*m+1] = __builtin_amdgcn_mfma_f32_16x16x16bf16_1k(
                  pa, bhi, oacc[2*m+1], 0, 0, 0);
            }
            oacc[8] = __builtin_amdgcn_mfma_f32_16x16x16bf16_1k(
                pa, ones, oacc[8], 0, 0, 0);
            __builtin_amdgcn_s_setprio(0);
          }
        }
      }
      __syncthreads();                         // buf^1 staged; buf reads done
    }

    // ---- epilogue: O / l, fp32 store (l already per-lane in row layout) ---
#pragma unroll
    for (int r = 0; r < 4; ++r) {
      const float inv = 1.0f / oacc[8][r];
      const size_t base = (size_t)(b*S_LEN + qw + quad*4 + r)*QSTRIDE
                        + h*DH + l15;
#pragma unroll
      for (int nd = 0; nd < 8; ++nd)
        og[base + nd*16] = oacc[nd][r] * inv;
    }
  }
}

extern "C" void kernel_launch(void* const* d_in, const int* in_sizes, int n_in,
                              void* d_out, int out_size, void* d_ws, size_t ws_size,
                              hipStream_t stream) {
  const float* q = (const float*)d_in[0];
  const float* k = (const float*)d_in[1];
  const float* v = (const float*)d_in[2];
  float* out = (float*)d_out;
  (void)d_ws; (void)ws_size;
  dim3 grid(8, HQ, 2);       // FROZEN: pairp fast, h, b (r5/r12 lesson)
  dim3 block(512);
  attn_fwd<<<grid, block, 0, stream>>>(q, k, v, out);
}